// Round 2
// baseline (504.349 us; speedup 1.0000x reference)
//
#include <hip/hip_runtime.h>

// out[b,c,h,w] = x[b,c, 2h+o, 2w+p],  (o,p) = divmod(i, 2)
// B=8, C=3, H=W=2048, Ho=Wo=1024.
//
// Each thread handles 4 consecutive output columns:
//   - two aligned 16B loads from the selected input row (32 B/lane)
//   - select components p / p+2 of each (p is wave-uniform -> no divergence)
//   - one 16B non-temporal store (output is streamed once, keep it out of L2)
// Grid-stride loop, 2048 blocks x 256 threads = full occupancy on 256 CUs.

#define HO    1024
#define WO    1024
#define W_IN  2048
#define WQ    256            // WO/4: float4-quads per output row

typedef float f4 __attribute__((ext_vector_type(4)));

__global__ __launch_bounds__(256)
void CNN2__57801669869865_kernel(const float* __restrict__ x,
                                 const int* __restrict__ i_ptr,
                                 float* __restrict__ out,
                                 int total_quads) {
    const int i = i_ptr[0];
    const int o = (i >> 1) & 1;   // row offset within 2x2 block
    const int p = i & 1;          // col offset within 2x2 block

    const int stride = gridDim.x * blockDim.x;
    for (int idx = blockIdx.x * blockDim.x + threadIdx.x;
         idx < total_quads;
         idx += stride) {

        const int wq  = idx & (WQ - 1);      // which output quad along the row
        const int row = idx >> 8;            // (b*C + c)*Ho + h
        const int bc  = row >> 10;           // row / 1024
        const int h   = row & (HO - 1);

        // input row 2h+o of image bc; quads 2wq, 2wq+1 cover cols 8wq..8wq+7
        const f4* src = reinterpret_cast<const f4*>(
            x + ((size_t)bc * W_IN + (size_t)(2 * h + o)) * W_IN) + 2 * wq;
        const f4 v0 = src[0];
        const f4 v1 = src[1];

        f4 r;
        r.x = p ? v0.y : v0.x;
        r.y = p ? v0.w : v0.z;
        r.z = p ? v1.y : v1.x;
        r.w = p ? v1.w : v1.z;

        f4* dst = reinterpret_cast<f4*>(out + (size_t)row * WO) + wq;
        __builtin_nontemporal_store(r, dst);
    }
}

extern "C" void kernel_launch(void* const* d_in, const int* in_sizes, int n_in,
                              void* d_out, int out_size, void* d_ws, size_t ws_size,
                              hipStream_t stream) {
    const float* x = (const float*)d_in[0];
    const int* ip  = (const int*)d_in[1];
    float* out     = (float*)d_out;

    const int total_quads = 8 * 3 * HO * WQ;   // 6,291,456
    const int block = 256;
    int grid = (total_quads + block - 1) / block;
    if (grid > 2048) grid = 2048;              // grid-stride; 8 blocks/CU

    CNN2__57801669869865_kernel<<<grid, block, 0, stream>>>(x, ip, out, total_quads);
}

// Round 3
// 502.018 us; speedup vs baseline: 1.0046x; 1.0046x over previous
//
#include <hip/hip_runtime.h>

// out[b,c,h,w] = x[b,c, 2h+o, 2w+p],  (o,p) = divmod(i, 2)
// B=8, C=3, H=W=2048, Ho=Wo=1024.
//
// Each thread handles 4 consecutive output columns:
//   - two aligned 16B loads from the selected input row (32 B/lane;
//     the 16-of-32B per-instruction stride is absorbed by L1 — the
//     sibling load of the same wave hits the already-fetched lines)
//   - select components p / p+2 of each (p is wave-uniform -> no divergence)
//   - one plain 16B store (NT store removed: no reuse to protect, and NT
//     write path measured ~12us slower on the 100MB output stream)
// Grid-stride loop, 2048 blocks x 256 threads = 8 blocks/CU full occupancy.

#define HO    1024
#define WO    1024
#define W_IN  2048
#define WQ    256            // WO/4: float4-quads per output row

typedef float f4 __attribute__((ext_vector_type(4)));

__global__ __launch_bounds__(256)
void CNN2__57801669869865_kernel(const float* __restrict__ x,
                                 const int* __restrict__ i_ptr,
                                 float* __restrict__ out,
                                 int total_quads) {
    const int i = i_ptr[0];
    const int o = (i >> 1) & 1;   // row offset within 2x2 block
    const int p = i & 1;          // col offset within 2x2 block

    const int stride = gridDim.x * blockDim.x;
    for (int idx = blockIdx.x * blockDim.x + threadIdx.x;
         idx < total_quads;
         idx += stride) {

        const int wq  = idx & (WQ - 1);      // which output quad along the row
        const int row = idx >> 8;            // (b*C + c)*Ho + h
        const int bc  = row >> 10;           // row / 1024
        const int h   = row & (HO - 1);

        // input row 2h+o of image bc; quads 2wq, 2wq+1 cover cols 8wq..8wq+7
        const f4* src = reinterpret_cast<const f4*>(
            x + ((size_t)bc * W_IN + (size_t)(2 * h + o)) * W_IN) + 2 * wq;
        const f4 v0 = src[0];
        const f4 v1 = src[1];

        f4 r;
        r.x = p ? v0.y : v0.x;
        r.y = p ? v0.w : v0.z;
        r.z = p ? v1.y : v1.x;
        r.w = p ? v1.w : v1.z;

        *(reinterpret_cast<f4*>(out + (size_t)row * WO) + wq) = r;
    }
}

extern "C" void kernel_launch(void* const* d_in, const int* in_sizes, int n_in,
                              void* d_out, int out_size, void* d_ws, size_t ws_size,
                              hipStream_t stream) {
    const float* x = (const float*)d_in[0];
    const int* ip  = (const int*)d_in[1];
    float* out     = (float*)d_out;

    const int total_quads = 8 * 3 * HO * WQ;   // 6,291,456
    const int block = 256;
    int grid = (total_quads + block - 1) / block;
    if (grid > 2048) grid = 2048;              // grid-stride; 8 blocks/CU

    CNN2__57801669869865_kernel<<<grid, block, 0, stream>>>(x, ip, out, total_quads);
}

// Round 4
// 490.741 us; speedup vs baseline: 1.0277x; 1.0230x over previous
//
#include <hip/hip_runtime.h>

// out[b,c,h,w] = x[b,c, 2h+o, 2w+p],  (o,p) = divmod(i, 2)
// B=8, C=3, H=W=2048, Ho=Wo=1024.
// Each thread handles 2 consecutive output columns:
//   - one aligned float4 load from the selected input row (dense 16 B/lane
//     per instruction -> perfect per-instruction coalescing)
//   - select components p and p+2 (p is wave-uniform -> no divergence)
//   - one float2 store (dense 8 B/lane).
// This flat-index structure is the harness-verified best (491.8 us); the
// 2-quad/grid-stride variant measured +10 us (strided 32 B/lane loads).

#define WO_HALF 512          // Wo/2
#define HO      1024
#define W_IN    2048

__global__ __launch_bounds__(256)
void CNN2__57801669869865_kernel(const float* __restrict__ x,
                                 const int* __restrict__ i_ptr,
                                 float* __restrict__ out,
                                 int total_pairs) {
    const int i = i_ptr[0];
    const int o = (i >> 1) & 1;   // row offset within 2x2 block
    const int p = i & 1;          // col offset within 2x2 block

    int idx = blockIdx.x * blockDim.x + threadIdx.x;
    if (idx >= total_pairs) return;

    const int wpair = idx & (WO_HALF - 1);   // which float4 along the row
    const int row   = idx >> 9;              // (b*C + c)*Ho + h
    const int bc    = row >> 10;             // row / 1024
    const int h     = row & (HO - 1);

    // input row 2h+o of image bc; float4 index wpair covers cols 4w..4w+3
    const float4* src = reinterpret_cast<const float4*>(
        x + ((size_t)bc * W_IN + (size_t)(2 * h + o)) * W_IN) + wpair;
    float4 v = *src;

    float2 r;
    r.x = p ? v.y : v.x;
    r.y = p ? v.w : v.z;

    float2* dst = reinterpret_cast<float2*>(out + (size_t)row * 1024) + wpair;
    *dst = r;
}

extern "C" void kernel_launch(void* const* d_in, const int* in_sizes, int n_in,
                              void* d_out, int out_size, void* d_ws, size_t ws_size,
                              hipStream_t stream) {
    const float* x = (const float*)d_in[0];
    const int* ip  = (const int*)d_in[1];
    float* out     = (float*)d_out;

    const int total_pairs = 8 * 3 * HO * WO_HALF;  // 12,582,912
    const int block = 256;
    const int grid = (total_pairs + block - 1) / block;

    CNN2__57801669869865_kernel<<<grid, block, 0, stream>>>(x, ip, out, total_pairs);
}